// Round 10
// baseline (50.730 us; speedup 1.0000x reference)
//
#include <hip/hip_runtime.h>
#include <hip/hip_fp16.h>
#include <stdint.h>

// HashGridEncoder forward (Instant-NGP style), MI355X / gfx950.
// L=16 levels, T=2^15 entries/level, F=2 features, DIM=3.
//
// Structure (round 4): one block per (level, point-chunk); level's 32768-entry
// table slice staged in LDS as packed f16x2 (128KB), all gathers are LDS.
// bid = l*16 + c -> XCD = c%8: the 16 level-blocks of a chunk share an XCD so
// partial 8B writes per 128B out-line merge in L2 (WRITE_SIZE = 62.5MB).
//
// Round-10: rounds 5-9 showed burst-issue + lgkmcnt(0) drain per group leaves
// the wave stalled on its own 16-read LDS-pipe serialization (~983 cyc/row at
// 4 waves/SIMD, all pipes <=35%). Fix = T3/T4 pattern on lgkmcnt: ROLLING
// pipeline, depth 2 rows: issue row r+1's 8 asm ds_reads, do weights(r) +
// x prefetch(r+2), then s_waitcnt lgkmcnt(8) — waits ONLY for row r's reads,
// row r+1's stay in flight. Counter never drains to 0 in the main loop.
// Falsifier: VGPR must rise to ~65-90 (16 in-flight dest regs forced live).

constexpr int      kL  = 16;
constexpr int      kT  = 32768;           // 2^15
constexpr uint32_t kM  = kT - 1;
constexpr uint32_t kP1 = 2654435761u;
constexpr uint32_t kP2 = 805459861u;
constexpr int      kNC = 16;              // point chunks (multiple of 8)
constexpr int      kBT = 1024;            // threads per block

typedef float f32x2 __attribute__((ext_vector_type(2)));
typedef __attribute__((address_space(3))) uint32_t u32_lds;

// scales[l] = 16 * 2^(l/3) - 1  (B = 2^(1/3) exactly), f64-rounded to f32.
__device__ __constant__ float c_scales[kL] = {
    15.0f,
    19.158736798317972f,
    24.398416831491190f,
    31.0f,
    39.317473596635944f,
    49.796833662982380f,
    63.0f,
    79.634947193271890f,
    100.59366732596477f,
    127.0f,
    160.26989438654378f,
    202.18733465192953f,
    255.0f,
    321.53978877308750f,
    405.37466930385903f,
    511.0f
};

__device__ __forceinline__ void load3c(float (&v)[3], const float* __restrict__ x,
                                       int n, int nmax) {
    int m = min(n, nmax);
    v[0] = x[m * 3 + 0];
    v[1] = x[m * 3 + 1];
    v[2] = x[m * 3 + 2];
}

// hash the point: keep fr[] for weights, compute the 8 LDS BYTE ADDRESSES.
// pos = x*(s/2) + (s/2 + 0.5)  (one FMA per dim)
__device__ __forceinline__ void hash_addr(
    uint32_t lbase, float A, float C, const float (&xv)[3],
    float (&fr)[3], uint32_t (&adr)[8])
{
    float p0 = fmaf(xv[0], A, C);
    float p1 = fmaf(xv[1], A, C);
    float p2 = fmaf(xv[2], A, C);

    float fl0 = floorf(p0), fl1 = floorf(p1), fl2 = floorf(p2);
    fr[0] = p0 - fl0;  fr[1] = p1 - fl1;  fr[2] = p2 - fl2;

    uint32_t g0 = (uint32_t)(int)fl0;
    uint32_t g1 = (uint32_t)(int)fl1;
    uint32_t g2 = (uint32_t)(int)fl2;

    uint32_t g0p = g0 + 1u;
    uint32_t hy0 = g1 * kP1;  uint32_t hy1 = hy0 + kP1;
    uint32_t hz0 = g2 * kP2;  uint32_t hz1 = hz0 + kP2;

    uint32_t hyz0 = hy0 ^ hz0;
    uint32_t hyz1 = hy1 ^ hz0;
    uint32_t hyz2 = hy0 ^ hz1;
    uint32_t hyz3 = hy1 ^ hz1;

    adr[0] = lbase + (((g0  ^ hyz0) & kM) << 2);
    adr[1] = lbase + (((g0p ^ hyz0) & kM) << 2);
    adr[2] = lbase + (((g0  ^ hyz1) & kM) << 2);
    adr[3] = lbase + (((g0p ^ hyz1) & kM) << 2);
    adr[4] = lbase + (((g0  ^ hyz2) & kM) << 2);
    adr[5] = lbase + (((g0p ^ hyz2) & kM) << 2);
    adr[6] = lbase + (((g0  ^ hyz3) & kM) << 2);
    adr[7] = lbase + (((g0p ^ hyz3) & kM) << 2);
}

// ISSUE 8 ds_read_b32 via inline asm — unmovable, stays in flight.
__device__ __forceinline__ void issue_asm8(const uint32_t (&adr)[8], uint32_t (&e)[8]) {
    asm volatile(
        "ds_read_b32 %0, %8\n\t"
        "ds_read_b32 %1, %9\n\t"
        "ds_read_b32 %2, %10\n\t"
        "ds_read_b32 %3, %11\n\t"
        "ds_read_b32 %4, %12\n\t"
        "ds_read_b32 %5, %13\n\t"
        "ds_read_b32 %6, %14\n\t"
        "ds_read_b32 %7, %15"
        : "=&v"(e[0]), "=&v"(e[1]), "=&v"(e[2]), "=&v"(e[3]),
          "=&v"(e[4]), "=&v"(e[5]), "=&v"(e[6]), "=&v"(e[7])
        : "v"(adr[0]), "v"(adr[1]), "v"(adr[2]), "v"(adr[3]),
          "v"(adr[4]), "v"(adr[5]), "v"(adr[6]), "v"(adr[7]));
}

// weight math (independent of loads) — f32 corner weights.
__device__ __forceinline__ void weights8(const float (&fr)[3], float (&wf)[8]) {
    float wx0 = 1.0f - fr[0];
    float wy0 = 1.0f - fr[1];
    float wz0 = 1.0f - fr[2];
    float wyz0 = wy0   * wz0;
    float wyz1 = fr[1] * wz0;
    float wyz2 = wy0   * fr[2];
    float wyz3 = fr[1] * fr[2];
    wf[0] = wx0   * wyz0;  wf[1] = fr[0] * wyz0;
    wf[2] = wx0   * wyz1;  wf[3] = fr[0] * wyz1;
    wf[4] = wx0   * wyz2;  wf[5] = fr[0] * wyz2;
    wf[6] = wx0   * wyz3;  wf[7] = fr[0] * wyz3;
}

__device__ __forceinline__ f32x2 consume8(const uint32_t (&e)[8], const float (&wf)[8]) {
    __half2 acc = __float2half2_rn(0.0f);
#pragma unroll
    for (int cc = 0; cc < 8; ++cc) {
        __half2 h = *reinterpret_cast<const __half2*>(&e[cc]);
        acc = __hfma2(__float2half2_rn(wf[cc]), h, acc);
    }
    f32x2 r;
    r.x = __low2float(acc);
    r.y = __high2float(acc);
    return r;
}

// One pipeline step: consume row r (in frCur/eCur), issue row r+1 (from xIss
// into frNew/eNew), prefetch x for row r+2 into xPref. Counted lgkmcnt(8):
// waits for row r's reads only; row r+1's 8 stay in flight.
template<bool GUARD>
__device__ __forceinline__ void pipe_body(
    uint32_t lbase, float A, float C,
    const float* __restrict__ x, f32x2* __restrict__ out,
    int n, int l, int lim, int nmax,
    float (&frCur)[3], uint32_t (&eCur)[8],
    const float (&xIss)[3], float (&frNew)[3], uint32_t (&eNew)[8],
    float (&xPref)[3])
{
    uint32_t adr[8];
    hash_addr(lbase, A, C, xIss, frNew, adr);
    issue_asm8(adr, eNew);
    __builtin_amdgcn_sched_barrier(0);

    float wf[8];
    weights8(frCur, wf);
    load3c(xPref, x, n + 2 * kBT, nmax);

    asm volatile("s_waitcnt lgkmcnt(8)" ::: "memory");
    __builtin_amdgcn_sched_barrier(0);
    f32x2 r = consume8(eCur, wf);
    if (!GUARD || n < lim) out[(size_t)n * kL + l] = r;
}

__device__ __forceinline__ void epilogue(
    const float (&fr)[3], const uint32_t (&e)[8],
    f32x2* __restrict__ out, int n, int l, int lim)
{
    float wf[8];
    weights8(fr, wf);
    asm volatile("s_waitcnt lgkmcnt(0)" ::: "memory");
    __builtin_amdgcn_sched_barrier(0);
    f32x2 r = consume8(e, wf);
    if (n < lim) out[(size_t)n * kL + l] = r;
}

__global__ __launch_bounds__(kBT, 4) void hashgrid_fwd(
    const float*  __restrict__ x,      // (N,3)
    const float2* __restrict__ table,  // (L,T) of float2
    f32x2*        __restrict__ out,    // (N,L) of float2
    int n_points, int chunk_sz)
{
    __shared__ uint32_t ltab[kT];      // 128 KB: level slice as packed f16x2

    int bid = blockIdx.x;
    int l   = bid >> 4;                // bid = l*16 + c  -> XCD = c%8
    int c   = bid & 15;

    // ---- stage level slice: 32768 f32x2 -> packed f16x2 (float4 loads) ----
    const float4* tsrc4 = reinterpret_cast<const float4*>(table + (size_t)l * kT);
    for (int e = threadIdx.x; e < kT / 2; e += kBT) {
        float4 q = tsrc4[e];
        uint2 pp;
        pp.x = ((uint32_t)__half_as_ushort(__float2half_rn(q.y)) << 16)
             |  (uint32_t)__half_as_ushort(__float2half_rn(q.x));
        pp.y = ((uint32_t)__half_as_ushort(__float2half_rn(q.w)) << 16)
             |  (uint32_t)__half_as_ushort(__float2half_rn(q.z));
        *reinterpret_cast<uint2*>(&ltab[e * 2]) = pp;
    }
    __syncthreads();

    // LDS byte offset of ltab (AS(3) cast -> 32-bit LDS address)
    uint32_t lbase = (uint32_t)(uintptr_t)(u32_lds*)ltab;

    float s = c_scales[l];
    float A = s * 0.5f;
    float C = fmaf(s, 0.5f, 0.5f);

    int tid  = (int)threadIdx.x;
    int base = c * chunk_sz;
    int lim  = min(base + chunk_sz, n_points);
    int nmax = n_points - 1;

    int span  = lim - base;                   // 31250
    int rows  = (span + kBT - 1) / kBT;       // 31
    int main2 = (rows - 1) & ~1;              // 30 unguarded rows (even count)

    float    xA[3], xB[3], frA[3], frB[3];
    uint32_t eA[8], eB[8];

    int n = base + tid;
    load3c(xA, x, n,       nmax);             // row 0
    load3c(xB, x, n + kBT, nmax);             // row 1
    {
        uint32_t adr[8];
        hash_addr(lbase, A, C, xA, frA, adr);
        issue_asm8(adr, eA);                  // row 0 in flight
    }

    for (int r = 0; r < main2; r += 2) {
        pipe_body<false>(lbase, A, C, x, out, n,       l, lim, nmax,
                         frA, eA, xB, frB, eB, xA);
        pipe_body<false>(lbase, A, C, x, out, n + kBT, l, lim, nmax,
                         frB, eB, xA, frA, eA, xB);
        n += 2 * kBT;
    }

    if (main2 != rows - 1) {
        // odd leftover row: consume it guarded, then epilogue on the next
        pipe_body<true>(lbase, A, C, x, out, n, l, lim, nmax,
                        frA, eA, xB, frB, eB, xA);
        epilogue(frB, eB, out, n + kBT, l, lim);
    } else {
        epilogue(frA, eA, out, n, l, lim);
    }
}

extern "C" void kernel_launch(void* const* d_in, const int* in_sizes, int n_in,
                              void* d_out, int out_size, void* d_ws, size_t ws_size,
                              hipStream_t stream) {
    const float*  x     = (const float*)d_in[0];
    const float2* table = (const float2*)d_in[1];
    f32x2*        out   = (f32x2*)d_out;

    int n_points = in_sizes[0] / 3;                  // (N,3) flat
    int chunk_sz = (n_points + kNC - 1) / kNC;       // 31250 for N=500000
    int blocks   = kL * kNC;                         // 256 = 1 per CU

    hashgrid_fwd<<<blocks, kBT, 0, stream>>>(x, table, out, n_points, chunk_sz);
}

// Round 11
// 50.008 us; speedup vs baseline: 1.0144x; 1.0144x over previous
//
#include <hip/hip_runtime.h>
#include <hip/hip_fp16.h>
#include <stdint.h>

// HashGridEncoder forward (Instant-NGP style), MI355X / gfx950.
// L=16 levels, T=2^15 entries/level, F=2 features, DIM=3.
//
// Structure (round 4): one block per (level, point-chunk); level's 32768-entry
// table slice staged in LDS as packed f16x2 (128KB), all gathers are LDS.
// bid = l*16 + c -> XCD = c%8: 16 level-blocks of a chunk share an XCD so the
// partial 8B writes per 128B out-line merge in L2 (WRITE_SIZE = 62.5MB).
//
// Round-11: rounds 5-10 pinned at ~970cyc/row for ANY lgkm scheduling ->
// the stall is VMCNT: on CDNA vmcnt counts STORES too (in-order retirement),
// so the compiler's per-row wait for the x-load drains the previous rows'
// scattered 64-line store acks (~200-400cyc) every row. Fix: ALL loop memory
// ops in inline asm with counted waits that never drain:
//   - x prefetch distance 2 (3 rotating slots), rows 0-2 issued BEFORE
//     __syncthreads (its vmcnt(0) pays them once)
//   - steady body: s_waitcnt vmcnt(4)  (2 newer x-loads + 2 stores in flight)
//   - rolling ds pipeline: s_waitcnt lgkmcnt(8) (next row's 8 stay in flight)
// 6-body unroll (3 x-slots x 2 e-slots); 30 iters = 5 sextuples exactly.

constexpr int      kL  = 16;
constexpr int      kT  = 32768;           // 2^15
constexpr uint32_t kM  = kT - 1;
constexpr uint32_t kP1 = 2654435761u;
constexpr uint32_t kP2 = 805459861u;
constexpr int      kNC = 16;              // point chunks (multiple of 8)
constexpr int      kBT = 1024;            // threads per block

typedef float f32x2 __attribute__((ext_vector_type(2)));
typedef __attribute__((address_space(3))) uint32_t u32_lds;

struct X3 { f32x2 xy; float z; };

// scales[l] = 16 * 2^(l/3) - 1  (B = 2^(1/3) exactly), f64-rounded to f32.
__device__ __constant__ float c_scales[kL] = {
    15.0f,
    19.158736798317972f,
    24.398416831491190f,
    31.0f,
    39.317473596635944f,
    49.796833662982380f,
    63.0f,
    79.634947193271890f,
    100.59366732596477f,
    127.0f,
    160.26989438654378f,
    202.18733465192953f,
    255.0f,
    321.53978877308750f,
    405.37466930385903f,
    511.0f
};

// ---- asm memory primitives (unmovable; counted waits stay valid) ----
__device__ __forceinline__ void xload_asm(const float* p, X3& v) {
    asm volatile("global_load_dwordx2 %0, %2, off\n\t"
                 "global_load_dword %1, %2, off offset:8"
                 : "=&v"(v.xy), "=&v"(v.z)
                 : "v"(p)
                 : "memory");
}

__device__ __forceinline__ void store_asm(void* p, f32x2 r) {
    asm volatile("global_store_dwordx2 %0, %1, off"
                 :: "v"(p), "v"(r)
                 : "memory");
}

__device__ __forceinline__ void issue_asm8(const uint32_t (&adr)[8], uint32_t (&e)[8]) {
    asm volatile(
        "ds_read_b32 %0, %8\n\t"
        "ds_read_b32 %1, %9\n\t"
        "ds_read_b32 %2, %10\n\t"
        "ds_read_b32 %3, %11\n\t"
        "ds_read_b32 %4, %12\n\t"
        "ds_read_b32 %5, %13\n\t"
        "ds_read_b32 %6, %14\n\t"
        "ds_read_b32 %7, %15"
        : "=&v"(e[0]), "=&v"(e[1]), "=&v"(e[2]), "=&v"(e[3]),
          "=&v"(e[4]), "=&v"(e[5]), "=&v"(e[6]), "=&v"(e[7])
        : "v"(adr[0]), "v"(adr[1]), "v"(adr[2]), "v"(adr[3]),
          "v"(adr[4]), "v"(adr[5]), "v"(adr[6]), "v"(adr[7]));
}

#define WAIT_VM4   do { asm volatile("s_waitcnt vmcnt(4)" ::: "memory"); \
                        __builtin_amdgcn_sched_barrier(0); } while (0)
#define WAIT_LGKM8 do { asm volatile("s_waitcnt lgkmcnt(8)" ::: "memory"); \
                        __builtin_amdgcn_sched_barrier(0); } while (0)
#define WAIT_LGKM0 do { asm volatile("s_waitcnt lgkmcnt(0)" ::: "memory"); \
                        __builtin_amdgcn_sched_barrier(0); } while (0)

// hash: keep fr[] for weights; produce the 8 LDS byte addresses.
__device__ __forceinline__ void hash_addr(
    uint32_t lbase, float A, float Cc, const X3& xv,
    float (&fr)[3], uint32_t (&adr)[8])
{
    float p0 = fmaf(xv.xy.x, A, Cc);
    float p1 = fmaf(xv.xy.y, A, Cc);
    float p2 = fmaf(xv.z,    A, Cc);

    float fl0 = floorf(p0), fl1 = floorf(p1), fl2 = floorf(p2);
    fr[0] = p0 - fl0;  fr[1] = p1 - fl1;  fr[2] = p2 - fl2;

    uint32_t g0 = (uint32_t)(int)fl0;
    uint32_t g1 = (uint32_t)(int)fl1;
    uint32_t g2 = (uint32_t)(int)fl2;

    uint32_t g0p = g0 + 1u;
    uint32_t hy0 = g1 * kP1;  uint32_t hy1 = hy0 + kP1;
    uint32_t hz0 = g2 * kP2;  uint32_t hz1 = hz0 + kP2;

    uint32_t hyz0 = hy0 ^ hz0;
    uint32_t hyz1 = hy1 ^ hz0;
    uint32_t hyz2 = hy0 ^ hz1;
    uint32_t hyz3 = hy1 ^ hz1;

    adr[0] = lbase + (((g0  ^ hyz0) & kM) << 2);
    adr[1] = lbase + (((g0p ^ hyz0) & kM) << 2);
    adr[2] = lbase + (((g0  ^ hyz1) & kM) << 2);
    adr[3] = lbase + (((g0p ^ hyz1) & kM) << 2);
    adr[4] = lbase + (((g0  ^ hyz2) & kM) << 2);
    adr[5] = lbase + (((g0p ^ hyz2) & kM) << 2);
    adr[6] = lbase + (((g0  ^ hyz3) & kM) << 2);
    adr[7] = lbase + (((g0p ^ hyz3) & kM) << 2);
}

__device__ __forceinline__ void weights8(const float (&fr)[3], float (&wf)[8]) {
    float wx0 = 1.0f - fr[0];
    float wy0 = 1.0f - fr[1];
    float wz0 = 1.0f - fr[2];
    float wyz0 = wy0   * wz0;
    float wyz1 = fr[1] * wz0;
    float wyz2 = wy0   * fr[2];
    float wyz3 = fr[1] * fr[2];
    wf[0] = wx0   * wyz0;  wf[1] = fr[0] * wyz0;
    wf[2] = wx0   * wyz1;  wf[3] = fr[0] * wyz1;
    wf[4] = wx0   * wyz2;  wf[5] = fr[0] * wyz2;
    wf[6] = wx0   * wyz3;  wf[7] = fr[0] * wyz3;
}

__device__ __forceinline__ f32x2 consume8(const uint32_t (&e)[8], const float (&wf)[8]) {
    __half2 acc = __float2half2_rn(0.0f);
#pragma unroll
    for (int cc = 0; cc < 8; ++cc) {
        __half2 h = *reinterpret_cast<const __half2*>(&e[cc]);
        acc = __hfma2(__float2half2_rn(wf[cc]), h, acc);
    }
    f32x2 r;
    r.x = __low2float(acc);
    r.y = __high2float(acc);
    return r;
}

// One steady iteration (row n): wait x(n+1) [vmcnt(4)], hash it + issue its
// ds reads, prefetch x(n+3), weights(n), wait row n's reads [lgkmcnt(8)],
// consume + store row n. All memory ops asm; counters never drain.
__device__ __forceinline__ void body(
    uint32_t lbase, float A, float Cc,
    const float* __restrict__ x, int& n, int nmax, char*& op,
    const X3& xHash, X3& xFree,
    float (&frC)[3], uint32_t (&eC)[8],
    float (&frN)[3], uint32_t (&eN)[8])
{
    WAIT_VM4;                                    // x(n+1) retired
    uint32_t adr[8];
    hash_addr(lbase, A, Cc, xHash, frN, adr);
    issue_asm8(adr, eN);                         // row n+1 reads in flight
    __builtin_amdgcn_sched_barrier(0);

    xload_asm(x + 3 * (size_t)min(n + 3 * kBT, nmax), xFree);   // x(n+3)
    float wf[8];
    weights8(frC, wf);

    WAIT_LGKM8;                                  // row n's 8 ready; n+1's fly
    f32x2 r = consume8(eC, wf);
    store_asm(op, r);                            // scattered store; NOT waited

    n  += kBT;
    op += (size_t)kBT * kL * sizeof(f32x2);
}

__global__ __launch_bounds__(kBT, 4) void hashgrid_fwd(
    const float*  __restrict__ x,      // (N,3)
    const float2* __restrict__ table,  // (L,T) of float2
    f32x2*        __restrict__ out,    // (N,L) of float2
    int n_points, int chunk_sz)
{
    __shared__ uint32_t ltab[kT];      // 128 KB: level slice as packed f16x2

    int bid = blockIdx.x;
    int l   = bid >> 4;                // bid = l*16 + c  -> XCD = c%8
    int c   = bid & 15;

    int tid  = (int)threadIdx.x;
    int base = c * chunk_sz;
    int lim  = min(base + chunk_sz, n_points);
    int nmax = n_points - 1;

    // ---- issue x prefetch for rows 0..2 BEFORE staging: the barrier's own
    //      vmcnt(0) drain pays their latency alongside the staging loads ----
    int n = base + tid;
    X3 xS0, xS1, xS2;
    xload_asm(x + 3 * (size_t)min(n,           nmax), xS0);
    xload_asm(x + 3 * (size_t)min(n +     kBT, nmax), xS1);
    xload_asm(x + 3 * (size_t)min(n + 2 * kBT, nmax), xS2);

    // ---- stage level slice: 32768 f32x2 -> packed f16x2 (float4 loads) ----
    const float4* tsrc4 = reinterpret_cast<const float4*>(table + (size_t)l * kT);
    for (int e = tid; e < kT / 2; e += kBT) {
        float4 q = tsrc4[e];
        uint2 pp;
        pp.x = ((uint32_t)__half_as_ushort(__float2half_rn(q.y)) << 16)
             |  (uint32_t)__half_as_ushort(__float2half_rn(q.x));
        pp.y = ((uint32_t)__half_as_ushort(__float2half_rn(q.w)) << 16)
             |  (uint32_t)__half_as_ushort(__float2half_rn(q.z));
        *reinterpret_cast<uint2*>(&ltab[e * 2]) = pp;
    }
    __syncthreads();                   // drains vmcnt(0): xS0..xS2 ready

    uint32_t lbase = (uint32_t)(uintptr_t)(u32_lds*)ltab;
    float s  = c_scales[l];
    float A  = s * 0.5f;
    float Cc = fmaf(s, 0.5f, 0.5f);

    int span  = lim - base;                    // 31250
    int rows  = (span + kBT - 1) / kBT;        // 31
    int iters = rows - 1;                      // 30
    int sext  = iters / 6;                     // 5

    float    frA[3], frB[3];
    uint32_t eA[8], eB[8];

    {   // prologue: hash row 0, put its reads in flight
        uint32_t adr[8];
        hash_addr(lbase, A, Cc, xS0, frA, adr);
        issue_asm8(adr, eA);
    }

    char* op = (char*)(out + (size_t)n * kL + l);

    // 6-body unroll: x-slot period 3 (hash S[(j+1)%3], refill S[j%3]),
    // e-slot period 2 (consume A/B alternating). lcm = 6; 30 iters = 5x6.
    for (int t = 0; t < sext; ++t) {
        body(lbase, A, Cc, x, n, nmax, op, xS1, xS0, frA, eA, frB, eB); // j%6=0
        body(lbase, A, Cc, x, n, nmax, op, xS2, xS1, frB, eB, frA, eA); // j%6=1
        body(lbase, A, Cc, x, n, nmax, op, xS0, xS2, frA, eA, frB, eB); // j%6=2
        body(lbase, A, Cc, x, n, nmax, op, xS1, xS0, frB, eB, frA, eA); // j%6=3
        body(lbase, A, Cc, x, n, nmax, op, xS2, xS1, frA, eA, frB, eB); // j%6=4
        body(lbase, A, Cc, x, n, nmax, op, xS0, xS2, frB, eB, frA, eA); // j%6=5
    }

    // epilogue: pending row (6*sext) sits in frA/eA (period starts at A)
    {
        float wf[8];
        weights8(frA, wf);
        WAIT_LGKM0;
        f32x2 r = consume8(eA, wf);
        if (n < lim) out[(size_t)n * kL + l] = r;
        n += kBT;
    }

    // generic serial remainder (iters%6 != 0 shapes only; empty for N=500000)
    for (; n < lim; n += kBT) {
        X3 xv;
        int m = min(n, nmax);
        xv.xy.x = x[m * 3 + 0];
        xv.xy.y = x[m * 3 + 1];
        xv.z    = x[m * 3 + 2];
        float frv[3]; uint32_t adr[8], ev[8];
        hash_addr(lbase, A, Cc, xv, frv, adr);
        issue_asm8(adr, ev);
        float wf[8];
        weights8(frv, wf);
        WAIT_LGKM0;
        f32x2 r = consume8(ev, wf);
        out[(size_t)n * kL + l] = r;
    }
}

extern "C" void kernel_launch(void* const* d_in, const int* in_sizes, int n_in,
                              void* d_out, int out_size, void* d_ws, size_t ws_size,
                              hipStream_t stream) {
    const float*  x     = (const float*)d_in[0];
    const float2* table = (const float2*)d_in[1];
    f32x2*        out   = (f32x2*)d_out;

    int n_points = in_sizes[0] / 3;                  // (N,3) flat
    int chunk_sz = (n_points + kNC - 1) / kNC;       // 31250 for N=500000
    int blocks   = kL * kNC;                         // 256 = 1 per CU

    hashgrid_fwd<<<blocks, kBT, 0, stream>>>(x, table, out, n_points, chunk_sz);
}